// Round 23
// baseline (115.643 us; speedup 1.0000x reference)
//
#include <hip/hip_runtime.h>
#include <stdint.h>

#define A_NUM 9
#define H_FM 50
#define W_FM 80
#define HW (H_FM * W_FM)
#define N_ANCH (A_NUM * HW)            // 36000
#define PRE_NMS_N 6000
#define POST_NMS_N 300
#define NMS_TH 0.7f
#define MASK_W 94            // ceil(6000/64)
#define MASK_STRIDE 96
#define NBIN 4096
#define BIN_CAP 4096         // keys per bin segment in d_ws
#define NBD 141              // decode blocks (141*256 = 36096)
#define JT 12                // col tiles of 512 (8 words)
#define RT 47                // row tiles of 128 (47*128 = 6016)
#define MTILES (RT * JT)     // 564

typedef unsigned long long ull;

// base anchor widths/heights (verified vs generate_anchors with np.round half-to-even)
__constant__ float c_aw[9] = {184.f,368.f,736.f,128.f,256.f,512.f, 88.f,176.f,352.f};
__constant__ float c_ah[9] = { 96.f,192.f,384.f,128.f,256.f,512.f,176.f,352.f,704.f};

// Scratch state as device globals (.bss zero-init). Zero-invariant restored by
// the pipeline each call: g_hist by k_maskcol, g_dead/g_rowany by k_scan tail.
// Below-diagonal g_mask tiles are NEVER written (always zero by construction).
// NOTE (r14/r17 lesson): never issue many contended global atomics onto few
// cachelines (~20ns serialized per op per line). Aggregate in LDS first.
// NOTE (r20/r21/r22 lesson): maskcol is execution-bound; ILP per LDS load is
// the lever (2 rows/thread: -4.4us). This round: 4 rows/thread.
__device__ int    g_hist[NBIN];
__device__ ull    g_dead[MASK_STRIDE];
__device__ ull    g_rowany[MASK_STRIDE];
__device__ float4 g_boxes[N_ANCH];         // stored in t-order (a*HW + cell)
__device__ float4 g_props[PRE_NMS_N];
__device__ ull    g_mask[(size_t)PRE_NMS_N * MASK_STRIDE];
__device__ ull    g_colsup[MASK_W * 64];

// divide-free suppression predicate: iou > TH  <=>  (1+TH)*inter > TH*(ai+aj)
__device__ __forceinline__ bool sup_of(float4 bi, float ai, float4 bj, float aj) {
    float iw = fminf(bi.z, bj.z) - fmaxf(bi.x, bj.x) + 1.f;
    float ih = fminf(bi.w, bj.w) - fmaxf(bi.y, bj.y) + 1.f;
    iw = fmaxf(iw, 0.f);
    ih = fmaxf(ih, 0.f);
    float inter = iw * ih;
    return 1.7f * inter > 0.7f * (ai + aj);
}

__device__ __forceinline__ ull lowmask(int x) {   // bits [0, x)
    if (x <= 0) return 0ULL;
    if (x >= 64) return ~0ULL;
    return (1ULL << x) - 1ULL;
}

// ------------- decode (coalesced) + key + direct bin-bucket append -----------
__global__ __launch_bounds__(256) void k_decode(const float* __restrict__ scores,
                                                const float* __restrict__ deltas,
                                                const float* __restrict__ iminfo,
                                                ull* __restrict__ bins) {
    int t = blockIdx.x * 256 + threadIdx.x;  // t = a*HW + cell  (coalesced reads)
    if (t >= N_ANCH) return;
    int a    = t / HW;
    int cell = t - a * HW;
    int x    = cell % W_FM;
    int y    = cell / W_FM;

    float sc = scores[(A_NUM + a) * HW + cell];

    int dbase = (a * 4) * HW + cell;
    float d0 = deltas[dbase];
    float d1 = deltas[dbase + HW];
    float d2 = deltas[dbase + 2 * HW];
    float d3 = deltas[dbase + 3 * HW];
    d2 = fminf(fmaxf(d2, -10.f), 10.f);
    d3 = fminf(fmaxf(d3, -10.f), 10.f);

    float aw = c_aw[a], ah = c_ah[a];
    float acx = (float)(x * 16 + 8);
    float acy = (float)(y * 16 + 8);

    float pcx = d0 * aw + acx;
    float pcy = d1 * ah + acy;
    float pw  = expf(d2) * aw;
    float ph  = expf(d3) * ah;

    float x1 = pcx - 0.5f * pw;
    float y1 = pcy - 0.5f * ph;
    float x2 = pcx + 0.5f * pw;
    float y2 = pcy + 0.5f * ph;

    float imh = iminfo[0], imw = iminfo[1], ims = iminfo[2];
    x1 = fminf(fmaxf(x1, 0.f), imw - 1.f);
    y1 = fminf(fmaxf(y1, 0.f), imh - 1.f);
    x2 = fminf(fmaxf(x2, 0.f), imw - 1.f);
    y2 = fminf(fmaxf(y2, 0.f), imh - 1.f);

    float wsz = x2 - x1 + 1.f;
    float hsz = y2 - y1 + 1.f;
    float minsz = 16.f * ims;
    bool valid = (wsz >= minsz) && (hsz >= minsz);

    g_boxes[t] = make_float4(x1, y1, x2, y2);   // t-order: coalesced store

    unsigned int u   = __float_as_uint(sc);
    unsigned int asc = (u & 0x80000000u) ? ~u : (u | 0x80000000u);
    unsigned int dk  = ~asc;                 // ascending dk == descending score
    if (!valid) dk = 0xFF800000u;            // == key of -inf score (bin 4088)

    unsigned int ikey = (unsigned int)(cell * A_NUM + a);   // reference anchor order
    ull key = ((ull)dk << 32) | ikey;

    int bin  = (int)(dk >> 20);
    int slot = atomicAdd(&g_hist[bin], 1);
    if (slot < BIN_CAP) bins[(size_t)bin * BIN_CAP + slot] = key;
}

// -------- per-bin LDS bitonic sort + direct props/dead write (1 block/bin) ---
__global__ __launch_bounds__(256) void k_binsort(const ull* __restrict__ bins) {
    __shared__ ull sb[4096];
    __shared__ int red[256];
    int b = blockIdx.x;
    int cntf = g_hist[b];
    if (cntf == 0) return;
    int tid = threadIdx.x;

    // global rank base: s0 = sum hist[0..b)
    int part = 0;
    for (int j = tid; j < b; j += 256) part += g_hist[j];
    red[tid] = part;
    __syncthreads();
    for (int off = 128; off > 0; off >>= 1) {
        if (tid < off) red[tid] += red[tid + off];
        __syncthreads();
    }
    int s0 = red[0];
    if (s0 >= PRE_NMS_N) return;             // bin entirely beyond top-6000

    int cnt = (cntf < BIN_CAP) ? cntf : BIN_CAP;
    const ull* seg = bins + (size_t)b * BIN_CAP;

    int P = 2; while (P < cnt) P <<= 1;      // cnt<=4096 -> P<=4096
    for (int i = tid; i < P; i += 256) sb[i] = (i < cnt) ? seg[i] : ~0ULL;
    __syncthreads();
    for (int k2 = 2; k2 <= P; k2 <<= 1) {
        for (int j = k2 >> 1; j >= 1; j >>= 1) {
            for (int p = tid; p < (P >> 1); p += 256) {
                int i  = ((p & ~(j - 1)) << 1) | (p & (j - 1));
                int pr = i | j;
                bool up = ((i & k2) == 0);
                ull a = sb[i], c = sb[pr];
                if ((a > c) == up) { sb[i] = c; sb[pr] = a; }
            }
            __syncthreads();
        }
    }
    for (int i = tid; i < cnt; i += 256) {
        int r = s0 + i;
        if (r < PRE_NMS_N) {
            ull key = sb[i];
            unsigned int dk = (unsigned int)(key >> 32);
            if (dk < 0xFF800000u) {
                unsigned int ik = (unsigned int)key;           // cell*9 + a
                int tt = (int)(ik % A_NUM) * HW + (int)(ik / A_NUM);
                g_props[r] = g_boxes[tt];
            } else {
                g_props[r] = make_float4(0.f, 0.f, 0.f, 0.f);
                atomicOr(&g_dead[r >> 6], 1ULL << (r & 63));
            }
        }
    }
}

// -------- fused: mask matrix (128x512 tiles, 4 rows/thread) + rowany ---------
// -------- (LDS-aggregated, 2 words), colsup (words), hist-zero ---------------
__global__ __launch_bounds__(256) void k_maskcol() {
    __shared__ float4 sj[8 * 65];            // padded: word q at sj[q*65 + b]
    __shared__ float  sa[8 * 65];            // 0.7 * area
    __shared__ ull    s_row[2];              // block rowany bits (2 words)
    int vb = blockIdx.x;
    int tid = threadIdx.x;

    if (vb < 16) g_hist[vb * 256 + tid] = 0;     // re-zero hist (binsort done)
    // (vb<16 => by2=vb/12<=1 => rows<=255, cols>=511: never below-diagonal)

    if (vb < MTILES) {
        int by2 = vb / JT;                   // 128-row tile index (0..46)
        int bx  = vb % JT;

        // tile fully below diagonal: bits always 0, g_mask words never written
        if (bx * 512 + 511 <= by2 * 128) return;

        if (tid < 2) s_row[tid] = 0ULL;

        // stage 512 j-props + 0.7*areas, padded layout, coalesced
        int jbase = bx * 512;
        for (int c = tid; c < 512; c += 256) {
            int jj = jbase + c;
            float4 bjs = (jj < PRE_NMS_N) ? g_props[jj] : make_float4(0.f, 0.f, 0.f, 0.f);
            int q = c >> 6, r = c & 63;
            sj[q * 65 + r] = bjs;
            sa[q * 65 + r] = 0.7f * (bjs.z - bjs.x + 1.f) * (bjs.w - bjs.y + 1.f);
        }
        __syncthreads();

        // thread -> (row quad, word): 32 quads x 8 words = 256 threads.
        // Each LDS bj load feeds FOUR independent IoU chains (ILP).
        int wl = tid & 7;                    // word within tile (0..7)
        int rq = tid >> 3;                   // row quad (0..31)
        int i0 = by2 * 128 + rq * 4;
        int w  = bx * 8 + wl;

        ull rb0 = 0, rb1 = 0;
        if (w < MASK_W) {
            float4 bi0 = (i0     < PRE_NMS_N) ? g_props[i0]     : make_float4(0.f,0.f,0.f,0.f);
            float4 bi1 = (i0 + 1 < PRE_NMS_N) ? g_props[i0 + 1] : make_float4(0.f,0.f,0.f,0.f);
            float4 bi2 = (i0 + 2 < PRE_NMS_N) ? g_props[i0 + 2] : make_float4(0.f,0.f,0.f,0.f);
            float4 bi3 = (i0 + 3 < PRE_NMS_N) ? g_props[i0 + 3] : make_float4(0.f,0.f,0.f,0.f);
            float ta0 = 0.7f * (bi0.z - bi0.x + 1.f) * (bi0.w - bi0.y + 1.f);
            float ta1 = 0.7f * (bi1.z - bi1.x + 1.f) * (bi1.w - bi1.y + 1.f);
            float ta2 = 0.7f * (bi2.z - bi2.x + 1.f) * (bi2.w - bi2.y + 1.f);
            float ta3 = 0.7f * (bi3.z - bi3.x + 1.f) * (bi3.w - bi3.y + 1.f);

            int jstart = w * 64;
            int bs = i0 + 1 - jstart; if (bs < 0) bs = 0;
            int be = PRE_NMS_N - jstart; if (be > 64) be = 64;
            const float4* sw  = &sj[wl * 65];
            const float*  swa = &sa[wl * 65];
            ull b0m = 0, b1m = 0, b2m = 0, b3m = 0;
            for (int b = bs; b < be; ++b) {
                float4 bj = sw[b];
                float aj07 = swa[b];
                ull bit = 1ULL << b;
                float iw0 = fminf(bi0.z, bj.z) - fmaxf(bi0.x, bj.x) + 1.f;
                float ih0 = fminf(bi0.w, bj.w) - fmaxf(bi0.y, bj.y) + 1.f;
                if (1.7f * (fmaxf(iw0, 0.f) * fmaxf(ih0, 0.f)) > ta0 + aj07) b0m |= bit;
                float iw1 = fminf(bi1.z, bj.z) - fmaxf(bi1.x, bj.x) + 1.f;
                float ih1 = fminf(bi1.w, bj.w) - fmaxf(bi1.y, bj.y) + 1.f;
                if (1.7f * (fmaxf(iw1, 0.f) * fmaxf(ih1, 0.f)) > ta1 + aj07) b1m |= bit;
                float iw2 = fminf(bi2.z, bj.z) - fmaxf(bi2.x, bj.x) + 1.f;
                float ih2 = fminf(bi2.w, bj.w) - fmaxf(bi2.y, bj.y) + 1.f;
                if (1.7f * (fmaxf(iw2, 0.f) * fmaxf(ih2, 0.f)) > ta2 + aj07) b2m |= bit;
                float iw3 = fminf(bi3.z, bj.z) - fmaxf(bi3.x, bj.x) + 1.f;
                float ih3 = fminf(bi3.w, bj.w) - fmaxf(bi3.y, bj.y) + 1.f;
                if (1.7f * (fmaxf(iw3, 0.f) * fmaxf(ih3, 0.f)) > ta3 + aj07) b3m |= bit;
            }
            // rows i0+k require j > i0+k: clear bits below (i0+k+1-jstart)
            b1m &= ~lowmask(i0 + 2 - jstart);
            b2m &= ~lowmask(i0 + 3 - jstart);
            b3m &= ~lowmask(i0 + 4 - jstart);

#pragma unroll
            for (int k = 0; k < 4; ++k) {
                int ik = i0 + k;
                ull bits = (k == 0) ? b0m : (k == 1) ? b1m : (k == 2) ? b2m : b3m;
                if (ik < PRE_NMS_N) {
                    g_mask[(size_t)ik * MASK_STRIDE + w] = bits;
                    if (bits && w != (ik >> 6)) {
                        if (((ik >> 6) & 1) == (((by2 * 128) >> 6) & 1))
                            rb0 |= (1ULL << (ik & 63));
                        else
                            rb1 |= (1ULL << (ik & 63));
                    }
                }
            }
        }
        if (rb0) atomicOr(&s_row[0], rb0);   // LDS atomics (r17 lesson)
        if (rb1) atomicOr(&s_row[1], rb1);
        __syncthreads();
        if (tid < 2 && s_row[tid]) {
            int wword = by2 * 2 + tid;       // 128-row tile = rowany words 2*by2, +1
            if (wword < MASK_STRIDE) atomicOr(&g_rowany[wword], s_row[tid]);
        }
    } else {
        // colsup: one 64-box word per block (same predicate as mask)
        int w = vb - MTILES;                 // 0..93
        int gj = w * 64 + tid;
        if (tid < 64)
            sj[tid] = (gj < PRE_NMS_N) ? g_props[gj] : make_float4(0.f, 0.f, 0.f, 0.f);
        __syncthreads();
        if (tid < 64) {
            float4 bj = sj[tid];
            float aj = (bj.z - bj.x + 1.f) * (bj.w - bj.y + 1.f);
            ull bits = 0;
            for (int b = 0; b < tid; ++b) {
                float4 bi = sj[b];
                float ai = (bi.z - bi.x + 1.f) * (bi.w - bi.y + 1.f);
                if (sup_of(bi, ai, bj, aj)) bits |= (1ULL << b);
            }
            g_colsup[gj] = bits;
        }
    }
}

// ------- greedy scan: readlane broadcast, diag prefetch, ballot fixed point --
// Tail re-zeros g_dead/g_rowany (this kernel is their last reader).
#define BATCH 8
__global__ __launch_bounds__(256, 1) void k_scan(float* __restrict__ out) {
    __shared__ ull scol[MASK_W * 64];        // 48128 B
    __shared__ ull srow[MASK_W];
    __shared__ int s_kept[POST_NMS_N];
    __shared__ int s_kc;
    int tid = threadIdx.x;

    for (int i = tid; i < MASK_W * 64; i += 256) scol[i] = g_colsup[i];
    for (int i = tid; i < MASK_W; i += 256)      srow[i] = g_rowany[i];
    __syncthreads();

    if (tid < 64) {
        int lane = tid;
        ull rm0 = g_dead[lane];
        ull rm1 = (lane < MASK_W - 64) ? g_dead[64 + lane] : ~0ULL;
        if (lane == 29) rm1 |= 0xFFFF000000000000ULL;    // pad 6000..6015
        int kc = 0;
        int pw = -2;
        ull dnext = 0;

        for (;;) {
            ull avail0 = __ballot(~rm0 != 0ULL);
            ull avail1 = __ballot(~rm1 != 0ULL);
            int w;
            if (avail0)      w = __ffsll(avail0) - 1;
            else if (avail1) w = 63 + __ffsll(avail1);
            else break;

            // diag: use prefetched value when the speculation (next = pw+1) hit
            ull diag = (w == pw + 1) ? dnext : scol[(w << 6) + lane];
            // prefetch for the likely next word
            if (w + 1 < MASK_W) dnext = scol[((w + 1) << 6) + lane];
            pw = w;

            ull raw = srow[w];
            // broadcast rm word w to all lanes via readlane (uniform w, ~10cy)
            ull rmw = (w < 64) ? rm0 : rm1;
            int ri  = (w < 64) ? w : w - 64;
            unsigned clo = __builtin_amdgcn_readlane((unsigned)rmw, ri);
            unsigned chi = __builtin_amdgcn_readlane((unsigned)(rmw >> 32), ri);
            ull curw = ((ull)chi << 32) | clo;

            // intra-word greedy fixed point via ballots
            ull U = ~curw;
            ull K = 0;
            while (U) {
                ull UK = U | K;
                bool deadp = (diag & K)  != 0ULL;
                bool freep = (diag & UK) == 0ULL;
                ull nd = __ballot(deadp) & U;
                U &= ~nd;
                ull nk = __ballot(freep) & U;
                U &= ~nk;
                K |= nk;
                if (!nk && !nd) break;       // safety; cannot happen
            }

            int cnt  = __popcll(K);
            int take = min(cnt, POST_NMS_N - kc);
            if (K & (1ULL << lane)) {
                int pos = kc + __popcll(K & ((1ULL << lane) - 1ULL));
                if (pos < POST_NMS_N) s_kept[pos] = (w << 6) + lane;
            }
            kc += take;
            if (kc >= POST_NMS_N) break;

            if (w < 64) { if (lane == w)      rm0 = ~0ULL; }
            else        { if (lane == w - 64) rm1 = ~0ULL; }

            // batched parallel row-OR for kept rows with cross-word suppression
            ull need = K & raw;
            while (need) {
                int id[BATCH];
                int n = 0;
#pragma unroll
                for (int t2 = 0; t2 < BATCH; ++t2) {
                    id[t2] = 0;
                    if (need) { id[t2] = __ffsll(need) - 1; need &= need - 1; n = t2 + 1; }
                }
                ull v0[BATCH], v1[BATCH];
#pragma unroll
                for (int t2 = 0; t2 < BATCH; ++t2) {
                    const ull* __restrict__ row =
                        g_mask + (size_t)((w << 6) + id[t2]) * MASK_STRIDE;
                    v0[t2] = row[lane];
                    v1[t2] = (lane < MASK_W - 64) ? row[64 + lane] : 0ULL;
                }
                ull a0 = 0, a1 = 0;
#pragma unroll
                for (int t2 = 0; t2 < BATCH; ++t2) {
                    ull m = (t2 < n) ? ~0ULL : 0ULL;
                    a0 |= v0[t2] & m;
                    a1 |= v1[t2] & m;
                }
                rm0 |= a0;
                rm1 |= a1;
            }
        }
        if (lane == 0) s_kc = (kc < POST_NMS_N) ? kc : POST_NMS_N;
    }
    __syncthreads();

    // restore zero-invariant for next call (all reads of dead/rowany are done)
    for (int i = tid; i < MASK_STRIDE; i += 256) {
        g_dead[i] = 0ULL;
        g_rowany[i] = 0ULL;
    }

    int kcf = s_kc;
    for (int r = tid; r < POST_NMS_N; r += 256) {
        float4 p = make_float4(0.f, 0.f, 0.f, 0.f);
        if (r < kcf) p = g_props[s_kept[r]];
        out[r * 5 + 0] = 0.f;
        out[r * 5 + 1] = p.x;
        out[r * 5 + 2] = p.y;
        out[r * 5 + 3] = p.z;
        out[r * 5 + 4] = p.w;
    }
}

extern "C" void kernel_launch(void* const* d_in, const int* in_sizes, int n_in,
                              void* d_out, int out_size, void* d_ws, size_t ws_size,
                              hipStream_t stream) {
    const float* scores = (const float*)d_in[0];
    const float* deltas = (const float*)d_in[1];
    const float* iminfo = (const float*)d_in[2];
    float* out = (float*)d_out;
    ull* bins = (ull*)d_ws;                  // 4096 bins * 4096 keys * 8 B (sparse use)

    k_decode<<<NBD, 256, 0, stream>>>(scores, deltas, iminfo, bins);
    k_binsort<<<NBIN, 256, 0, stream>>>(bins);
    k_maskcol<<<MTILES + MASK_W, 256, 0, stream>>>();
    k_scan<<<1, 256, 0, stream>>>(out);
}

// Round 24
// 105.767 us; speedup vs baseline: 1.0934x; 1.0934x over previous
//
#include <hip/hip_runtime.h>
#include <stdint.h>

#define A_NUM 9
#define H_FM 50
#define W_FM 80
#define HW (H_FM * W_FM)
#define N_ANCH (A_NUM * HW)            // 36000
#define PRE_NMS_N 6000
#define POST_NMS_N 300
#define NMS_TH 0.7f
#define MASK_W 94            // ceil(6000/64)
#define MASK_STRIDE 96
#define NBIN 4096
#define BIN_CAP 4096         // keys per bin segment in d_ws
#define NBD 141              // decode blocks (141*256 = 36096)
#define JT 12                // col tiles of 512 (8 words)
#define MTILES (94 * JT)     // 1128

typedef unsigned long long ull;

// base anchor widths/heights (verified vs generate_anchors with np.round half-to-even)
__constant__ float c_aw[9] = {184.f,368.f,736.f,128.f,256.f,512.f, 88.f,176.f,352.f};
__constant__ float c_ah[9] = { 96.f,192.f,384.f,128.f,256.f,512.f,176.f,352.f,704.f};

// Scratch state as device globals (.bss zero-init). Zero-invariant restored by
// the pipeline each call: g_hist by k_maskcol, g_dead/g_rowany by k_scan tail.
// Below-diagonal g_mask tiles are NEVER written (always zero by construction).
// NOTE (r14/r17 lesson): never issue many contended global atomics onto few
// cachelines (~20ns serialized per op per line). Aggregate in LDS first.
// NOTE (r20/r21/r22/r23 lessons): maskcol is execution-bound; 2 rows/thread
// with 64x512 tiles is the measured optimum (4 rows coarsens diagonal-skip
// and regresses; write-shape changes are irrelevant).
__device__ int    g_hist[NBIN];
__device__ ull    g_dead[MASK_STRIDE];
__device__ ull    g_rowany[MASK_STRIDE];
__device__ float4 g_boxes[N_ANCH];         // stored in t-order (a*HW + cell)
__device__ float4 g_props[PRE_NMS_N];
__device__ ull    g_mask[(size_t)PRE_NMS_N * MASK_STRIDE];
__device__ ull    g_colsup[MASK_W * 64];

// divide-free suppression predicate: iou > TH  <=>  (1+TH)*inter > TH*(ai+aj)
__device__ __forceinline__ bool sup_of(float4 bi, float ai, float4 bj, float aj) {
    float iw = fminf(bi.z, bj.z) - fmaxf(bi.x, bj.x) + 1.f;
    float ih = fminf(bi.w, bj.w) - fmaxf(bi.y, bj.y) + 1.f;
    iw = fmaxf(iw, 0.f);
    ih = fmaxf(ih, 0.f);
    float inter = iw * ih;
    return 1.7f * inter > 0.7f * (ai + aj);
}

// ------------- decode (coalesced) + key + direct bin-bucket append -----------
__global__ __launch_bounds__(256) void k_decode(const float* __restrict__ scores,
                                                const float* __restrict__ deltas,
                                                const float* __restrict__ iminfo,
                                                ull* __restrict__ bins) {
    int t = blockIdx.x * 256 + threadIdx.x;  // t = a*HW + cell  (coalesced reads)
    if (t >= N_ANCH) return;
    int a    = t / HW;
    int cell = t - a * HW;
    int x    = cell % W_FM;
    int y    = cell / W_FM;

    float sc = scores[(A_NUM + a) * HW + cell];

    int dbase = (a * 4) * HW + cell;
    float d0 = deltas[dbase];
    float d1 = deltas[dbase + HW];
    float d2 = deltas[dbase + 2 * HW];
    float d3 = deltas[dbase + 3 * HW];
    d2 = fminf(fmaxf(d2, -10.f), 10.f);
    d3 = fminf(fmaxf(d3, -10.f), 10.f);

    float aw = c_aw[a], ah = c_ah[a];
    float acx = (float)(x * 16 + 8);
    float acy = (float)(y * 16 + 8);

    float pcx = d0 * aw + acx;
    float pcy = d1 * ah + acy;
    float pw  = expf(d2) * aw;
    float ph  = expf(d3) * ah;

    float x1 = pcx - 0.5f * pw;
    float y1 = pcy - 0.5f * ph;
    float x2 = pcx + 0.5f * pw;
    float y2 = pcy + 0.5f * ph;

    float imh = iminfo[0], imw = iminfo[1], ims = iminfo[2];
    x1 = fminf(fmaxf(x1, 0.f), imw - 1.f);
    y1 = fminf(fmaxf(y1, 0.f), imh - 1.f);
    x2 = fminf(fmaxf(x2, 0.f), imw - 1.f);
    y2 = fminf(fmaxf(y2, 0.f), imh - 1.f);

    float wsz = x2 - x1 + 1.f;
    float hsz = y2 - y1 + 1.f;
    float minsz = 16.f * ims;
    bool valid = (wsz >= minsz) && (hsz >= minsz);

    g_boxes[t] = make_float4(x1, y1, x2, y2);   // t-order: coalesced store

    unsigned int u   = __float_as_uint(sc);
    unsigned int asc = (u & 0x80000000u) ? ~u : (u | 0x80000000u);
    unsigned int dk  = ~asc;                 // ascending dk == descending score
    if (!valid) dk = 0xFF800000u;            // == key of -inf score (bin 4088)

    unsigned int ikey = (unsigned int)(cell * A_NUM + a);   // reference anchor order
    ull key = ((ull)dk << 32) | ikey;

    int bin  = (int)(dk >> 20);
    int slot = atomicAdd(&g_hist[bin], 1);
    if (slot < BIN_CAP) bins[(size_t)bin * BIN_CAP + slot] = key;
}

// -------- per-bin LDS bitonic sort + direct props/dead write (1 block/bin) ---
__global__ __launch_bounds__(256) void k_binsort(const ull* __restrict__ bins) {
    __shared__ ull sb[4096];
    __shared__ int red[256];
    int b = blockIdx.x;
    int cntf = g_hist[b];
    if (cntf == 0) return;
    int tid = threadIdx.x;

    // global rank base: s0 = sum hist[0..b)
    int part = 0;
    for (int j = tid; j < b; j += 256) part += g_hist[j];
    red[tid] = part;
    __syncthreads();
    for (int off = 128; off > 0; off >>= 1) {
        if (tid < off) red[tid] += red[tid + off];
        __syncthreads();
    }
    int s0 = red[0];
    if (s0 >= PRE_NMS_N) return;             // bin entirely beyond top-6000

    int cnt = (cntf < BIN_CAP) ? cntf : BIN_CAP;
    const ull* seg = bins + (size_t)b * BIN_CAP;

    int P = 2; while (P < cnt) P <<= 1;      // cnt<=4096 -> P<=4096
    for (int i = tid; i < P; i += 256) sb[i] = (i < cnt) ? seg[i] : ~0ULL;
    __syncthreads();
    for (int k2 = 2; k2 <= P; k2 <<= 1) {
        for (int j = k2 >> 1; j >= 1; j >>= 1) {
            for (int p = tid; p < (P >> 1); p += 256) {
                int i  = ((p & ~(j - 1)) << 1) | (p & (j - 1));
                int pr = i | j;
                bool up = ((i & k2) == 0);
                ull a = sb[i], c = sb[pr];
                if ((a > c) == up) { sb[i] = c; sb[pr] = a; }
            }
            __syncthreads();
        }
    }
    for (int i = tid; i < cnt; i += 256) {
        int r = s0 + i;
        if (r < PRE_NMS_N) {
            ull key = sb[i];
            unsigned int dk = (unsigned int)(key >> 32);
            if (dk < 0xFF800000u) {
                unsigned int ik = (unsigned int)key;           // cell*9 + a
                int tt = (int)(ik % A_NUM) * HW + (int)(ik / A_NUM);
                g_props[r] = g_boxes[tt];
            } else {
                g_props[r] = make_float4(0.f, 0.f, 0.f, 0.f);
                atomicOr(&g_dead[r >> 6], 1ULL << (r & 63));
            }
        }
    }
}

// -------- fused: mask matrix (64x512 tiles, 2 rows/thread) + rowany ----------
// -------- (LDS-aggregated), colsup (words), hist-zero ------------------------
__global__ __launch_bounds__(256) void k_maskcol() {
    __shared__ float4 sj[8 * 65];            // padded: word q at sj[q*65 + b]
    __shared__ float  sa[8 * 65];            // precomputed areas
    __shared__ ull    s_row;                 // block-aggregated rowany bits
    int vb = blockIdx.x;
    int tid = threadIdx.x;

    if (vb < 16) g_hist[vb * 256 + tid] = 0;     // re-zero hist (binsort done)
    // (vb<16 => by=vb/12<=1, never below-diagonal, so never early-returns)

    if (vb < MTILES) {
        int by = vb / JT;
        int bx = vb % JT;

        // tile fully below diagonal: bits always 0, g_mask words never written
        if (bx * 512 + 511 <= by * 64) return;

        if (tid == 0) s_row = 0ULL;

        // stage 512 j-props + areas, padded layout, coalesced
        int jbase = bx * 512;
        for (int c = tid; c < 512; c += 256) {
            int jj = jbase + c;
            float4 bjs = (jj < PRE_NMS_N) ? g_props[jj] : make_float4(0.f, 0.f, 0.f, 0.f);
            int q = c >> 6, r = c & 63;
            sj[q * 65 + r] = bjs;
            sa[q * 65 + r] = (bjs.z - bjs.x + 1.f) * (bjs.w - bjs.y + 1.f);
        }
        __syncthreads();

        // thread -> (row pair, word): 32 row-pairs x 8 words = 256 threads.
        // Each LDS bj/aj load feeds TWO independent IoU chains (ILP).
        int wl = tid & 7;                    // word within tile (0..7)
        int rp = tid >> 3;                   // row pair (0..31)
        int i0 = by * 64 + rp * 2;
        int i1 = i0 + 1;
        int w  = bx * 8 + wl;

        ull rowbits = 0;
        if (w < MASK_W) {
            bool act0 = (i0 < PRE_NMS_N);
            bool act1 = (i1 < PRE_NMS_N);
            float4 bi0 = act0 ? g_props[i0] : make_float4(0.f, 0.f, 0.f, 0.f);
            float4 bi1 = act1 ? g_props[i1] : make_float4(0.f, 0.f, 0.f, 0.f);
            float a0 = (bi0.z - bi0.x + 1.f) * (bi0.w - bi0.y + 1.f);
            float a1 = (bi1.z - bi1.x + 1.f) * (bi1.w - bi1.y + 1.f);

            int jstart = w * 64;
            int bs = i0 + 1 - jstart; if (bs < 0) bs = 0;
            int be = PRE_NMS_N - jstart; if (be > 64) be = 64;
            const float4* sw  = &sj[wl * 65];
            const float*  swa = &sa[wl * 65];
            ull bits0 = 0, bits1 = 0;
            for (int b = bs; b < be; ++b) {
                float4 bj = sw[b];
                float aj = swa[b];
                float iw0 = fminf(bi0.z, bj.z) - fmaxf(bi0.x, bj.x) + 1.f;
                float ih0 = fminf(bi0.w, bj.w) - fmaxf(bi0.y, bj.y) + 1.f;
                float in0 = fmaxf(iw0, 0.f) * fmaxf(ih0, 0.f);
                float iw1 = fminf(bi1.z, bj.z) - fmaxf(bi1.x, bj.x) + 1.f;
                float ih1 = fminf(bi1.w, bj.w) - fmaxf(bi1.y, bj.y) + 1.f;
                float in1 = fmaxf(iw1, 0.f) * fmaxf(ih1, 0.f);
                if (1.7f * in0 > 0.7f * (a0 + aj)) bits0 |= (1ULL << b);
                if (1.7f * in1 > 0.7f * (a1 + aj)) bits1 |= (1ULL << b);
            }
            // row i1: loop included j == i1 (self, IoU=1) -> clear that bit
            int bself = i1 - jstart;
            if (bself >= 0 && bself < 64) bits1 &= ~(1ULL << bself);

            if (act0) {
                g_mask[(size_t)i0 * MASK_STRIDE + w] = bits0;
                if (bits0 && w != (i0 >> 6)) rowbits |= (1ULL << (i0 & 63));
            }
            if (act1) {
                g_mask[(size_t)i1 * MASK_STRIDE + w] = bits1;
                if (bits1 && w != (i1 >> 6)) rowbits |= (1ULL << (i1 & 63));
            }
        }
        if (rowbits) atomicOr(&s_row, rowbits);      // LDS atomic (r17 lesson)
        __syncthreads();
        if (tid == 0 && s_row) atomicOr(&g_rowany[by], s_row);
    } else {
        // colsup: one 64-box word per block (same predicate as mask)
        int w = vb - MTILES;                 // 0..93
        int gj = w * 64 + tid;
        if (tid < 64)
            sj[tid] = (gj < PRE_NMS_N) ? g_props[gj] : make_float4(0.f, 0.f, 0.f, 0.f);
        __syncthreads();
        if (tid < 64) {
            float4 bj = sj[tid];
            float aj = (bj.z - bj.x + 1.f) * (bj.w - bj.y + 1.f);
            ull bits = 0;
            for (int b = 0; b < tid; ++b) {
                float4 bi = sj[b];
                float ai = (bi.z - bi.x + 1.f) * (bi.w - bi.y + 1.f);
                if (sup_of(bi, ai, bj, aj)) bits |= (1ULL << b);
            }
            g_colsup[gj] = bits;
        }
    }
}

// ------- greedy scan: readlane broadcast, diag prefetch, ballot fixed point --
// Tail re-zeros g_dead/g_rowany (this kernel is their last reader).
#define BATCH 8
__global__ __launch_bounds__(256, 1) void k_scan(float* __restrict__ out) {
    __shared__ ull scol[MASK_W * 64];        // 48128 B
    __shared__ ull srow[MASK_W];
    __shared__ int s_kept[POST_NMS_N];
    __shared__ int s_kc;
    int tid = threadIdx.x;

    for (int i = tid; i < MASK_W * 64; i += 256) scol[i] = g_colsup[i];
    for (int i = tid; i < MASK_W; i += 256)      srow[i] = g_rowany[i];
    __syncthreads();

    if (tid < 64) {
        int lane = tid;
        ull rm0 = g_dead[lane];
        ull rm1 = (lane < MASK_W - 64) ? g_dead[64 + lane] : ~0ULL;
        if (lane == 29) rm1 |= 0xFFFF000000000000ULL;    // pad 6000..6015
        int kc = 0;
        int pw = -2;
        ull dnext = 0;

        for (;;) {
            ull avail0 = __ballot(~rm0 != 0ULL);
            ull avail1 = __ballot(~rm1 != 0ULL);
            int w;
            if (avail0)      w = __ffsll(avail0) - 1;
            else if (avail1) w = 63 + __ffsll(avail1);
            else break;

            // diag: use prefetched value when the speculation (next = pw+1) hit
            ull diag = (w == pw + 1) ? dnext : scol[(w << 6) + lane];
            // prefetch for the likely next word
            if (w + 1 < MASK_W) dnext = scol[((w + 1) << 6) + lane];
            pw = w;

            ull raw = srow[w];
            // broadcast rm word w to all lanes via readlane (uniform w, ~10cy)
            ull rmw = (w < 64) ? rm0 : rm1;
            int ri  = (w < 64) ? w : w - 64;
            unsigned clo = __builtin_amdgcn_readlane((unsigned)rmw, ri);
            unsigned chi = __builtin_amdgcn_readlane((unsigned)(rmw >> 32), ri);
            ull curw = ((ull)chi << 32) | clo;

            // intra-word greedy fixed point via ballots
            ull U = ~curw;
            ull K = 0;
            while (U) {
                ull UK = U | K;
                bool deadp = (diag & K)  != 0ULL;
                bool freep = (diag & UK) == 0ULL;
                ull nd = __ballot(deadp) & U;
                U &= ~nd;
                ull nk = __ballot(freep) & U;
                U &= ~nk;
                K |= nk;
                if (!nk && !nd) break;       // safety; cannot happen
            }

            int cnt  = __popcll(K);
            int take = min(cnt, POST_NMS_N - kc);
            if (K & (1ULL << lane)) {
                int pos = kc + __popcll(K & ((1ULL << lane) - 1ULL));
                if (pos < POST_NMS_N) s_kept[pos] = (w << 6) + lane;
            }
            kc += take;
            if (kc >= POST_NMS_N) break;

            if (w < 64) { if (lane == w)      rm0 = ~0ULL; }
            else        { if (lane == w - 64) rm1 = ~0ULL; }

            // batched parallel row-OR for kept rows with cross-word suppression
            ull need = K & raw;
            while (need) {
                int id[BATCH];
                int n = 0;
#pragma unroll
                for (int t2 = 0; t2 < BATCH; ++t2) {
                    id[t2] = 0;
                    if (need) { id[t2] = __ffsll(need) - 1; need &= need - 1; n = t2 + 1; }
                }
                ull v0[BATCH], v1[BATCH];
#pragma unroll
                for (int t2 = 0; t2 < BATCH; ++t2) {
                    const ull* __restrict__ row =
                        g_mask + (size_t)((w << 6) + id[t2]) * MASK_STRIDE;
                    v0[t2] = row[lane];
                    v1[t2] = (lane < MASK_W - 64) ? row[64 + lane] : 0ULL;
                }
                ull a0 = 0, a1 = 0;
#pragma unroll
                for (int t2 = 0; t2 < BATCH; ++t2) {
                    ull m = (t2 < n) ? ~0ULL : 0ULL;
                    a0 |= v0[t2] & m;
                    a1 |= v1[t2] & m;
                }
                rm0 |= a0;
                rm1 |= a1;
            }
        }
        if (lane == 0) s_kc = (kc < POST_NMS_N) ? kc : POST_NMS_N;
    }
    __syncthreads();

    // restore zero-invariant for next call (all reads of dead/rowany are done)
    for (int i = tid; i < MASK_STRIDE; i += 256) {
        g_dead[i] = 0ULL;
        g_rowany[i] = 0ULL;
    }

    int kcf = s_kc;
    for (int r = tid; r < POST_NMS_N; r += 256) {
        float4 p = make_float4(0.f, 0.f, 0.f, 0.f);
        if (r < kcf) p = g_props[s_kept[r]];
        out[r * 5 + 0] = 0.f;
        out[r * 5 + 1] = p.x;
        out[r * 5 + 2] = p.y;
        out[r * 5 + 3] = p.z;
        out[r * 5 + 4] = p.w;
    }
}

extern "C" void kernel_launch(void* const* d_in, const int* in_sizes, int n_in,
                              void* d_out, int out_size, void* d_ws, size_t ws_size,
                              hipStream_t stream) {
    const float* scores = (const float*)d_in[0];
    const float* deltas = (const float*)d_in[1];
    const float* iminfo = (const float*)d_in[2];
    float* out = (float*)d_out;
    ull* bins = (ull*)d_ws;                  // 4096 bins * 4096 keys * 8 B (sparse use)

    k_decode<<<NBD, 256, 0, stream>>>(scores, deltas, iminfo, bins);
    k_binsort<<<NBIN, 256, 0, stream>>>(bins);
    k_maskcol<<<MTILES + MASK_W, 256, 0, stream>>>();
    k_scan<<<1, 256, 0, stream>>>(out);
}